// Round 3
// baseline (452.515 us; speedup 1.0000x reference)
//
#include <hip/hip_runtime.h>
#include <cstdint>

typedef __bf16 bf16;
typedef __bf16 bf16x8 __attribute__((ext_vector_type(8)));
typedef float  f32x4  __attribute__((ext_vector_type(4)));

#define BARRIER()    asm volatile("s_barrier" ::: "memory")
#define WAIT_LGKM0() do { asm volatile("s_waitcnt lgkmcnt(0)" ::: "memory"); \
                          __builtin_amdgcn_sched_barrier(0); } while (0)
#define WAIT_VM(n)   do { asm volatile("s_waitcnt vmcnt(" #n ")" ::: "memory"); \
                          __builtin_amdgcn_sched_barrier(0); } while (0)

// ---------------------------------------------------------------------------
// Stage 1a/1b: small fp32 GEMMs -> bf16 output.  C = A(MxK) @ B(KxN) [+bias]
// ---------------------------------------------------------------------------
__global__ __launch_bounds__(256) void gemm_small(
    const float* __restrict__ A, const float* __restrict__ Bm,
    const float* __restrict__ bias, bf16* __restrict__ Cout,
    int M, int N, int K)
{
    __shared__ float As[64][20];
    __shared__ float Bs[16][68];
    const int tid = threadIdx.x;
    const int m0 = blockIdx.x * 64, n0 = blockIdx.y * 64;
    const int tx = tid & 15, ty = tid >> 4;
    const int arow = tid >> 2, ak = (tid & 3) << 2;
    const int bk = tid >> 4, bc = (tid & 15) << 2;
    const bool avalid = (m0 + arow) < M;
    float acc[4][4] = {};

    for (int k0 = 0; k0 < K; k0 += 16) {
        float4 av = make_float4(0.f, 0.f, 0.f, 0.f);
        if (avalid) av = *(const float4*)&A[(size_t)(m0 + arow) * K + k0 + ak];
        float4 bv = *(const float4*)&Bm[(size_t)(k0 + bk) * N + n0 + bc];
        __syncthreads();
        *(float4*)&As[arow][ak] = av;
        *(float4*)&Bs[bk][bc] = bv;
        __syncthreads();
#pragma unroll
        for (int k = 0; k < 16; ++k) {
            float a[4], b[4];
#pragma unroll
            for (int i = 0; i < 4; ++i) a[i] = As[ty * 4 + i][k];
#pragma unroll
            for (int j = 0; j < 4; ++j) b[j] = Bs[k][tx * 4 + j];
#pragma unroll
            for (int i = 0; i < 4; ++i)
#pragma unroll
                for (int j = 0; j < 4; ++j) acc[i][j] += a[i] * b[j];
        }
    }
#pragma unroll
    for (int i = 0; i < 4; ++i) {
        int row = m0 + ty * 4 + i;
        if (row >= M) continue;
#pragma unroll
        for (int j = 0; j < 4; ++j) {
            int col = n0 + tx * 4 + j;
            float v = acc[i][j] + (bias ? bias[col] : 0.f);
            Cout[(size_t)row * N + col] = (bf16)v;
        }
    }
}

// ---------------------------------------------------------------------------
// Stage 1c: W2 (640x1024 fp32) -> W2T (1024x640 bf16)
// ---------------------------------------------------------------------------
__global__ __launch_bounds__(256) void w2_transpose(
    const float* __restrict__ W2, bf16* __restrict__ W2T)
{
    __shared__ float t[32][33];
    const int tx = threadIdx.x, ty = threadIdx.y;
    const int n0 = blockIdx.x * 32, k0 = blockIdx.y * 32;
#pragma unroll
    for (int i = 0; i < 4; ++i)
        t[ty + i * 8][tx] = W2[(size_t)(k0 + ty + i * 8) * 1024 + n0 + tx];
    __syncthreads();
#pragma unroll
    for (int i = 0; i < 4; ++i)
        W2T[(size_t)(n0 + ty + i * 8) * 640 + k0 + tx] = (bf16)t[tx][ty + i * 8];
}

// ---------------------------------------------------------------------------
// Stage 2: fused joint GEMM, 8-phase-style schedule (4 phases per K-tile),
// raw s_barrier + counted vmcnt (no __syncthreads in the loop).
// BM=256 BN=256 BK=64, 512 threads = 8 waves (2Mx4N), wave tile 128x64.
// LDS 128 KB double-buffered; XOR-swizzled 16B chunks (slot ^= row&7).
// Per tile t: P0 issues A-loads(t+1); P1/P2 each issue 2 B-DMA(t+1, back buf);
// each phase: [ds_reads | issues] barrier lgkm(0) setprio(1) 16xMFMA setprio(0)
// barrier. Tile tail: vmcnt(4) -> genA(t+1) -> vmcnt(0), lgkm(0), barrier.
// ---------------------------------------------------------------------------
__global__ __launch_bounds__(512, 2) void joint_main(
    const bf16* __restrict__ hf, const bf16* __restrict__ hgb,
    const bf16* __restrict__ W2T, const float* __restrict__ b2,
    float* __restrict__ out)
{
    __shared__ bf16 As[2][256 * 64];   // 2 x 32 KB
    __shared__ bf16 Bs[2][256 * 64];   // 2 x 32 KB
    const int tid = threadIdx.x;
    const int n0 = blockIdx.x * 256;
    const int m0 = blockIdx.y * 256;

    // --- A-generation mapping: thread -> (row r in half, k-quarter) ---
    const int r  = tid >> 2;               // 0..127
    const int kq = (tid & 3) << 4;         // 0,16,32,48
    const int c0 = (tid & 3) << 1;         // 16B-chunk indices c0, c0+1
    const int aoff0 = r * 64 + (((c0    ) ^ (r & 7)) << 3);
    const int aoff1 = r * 64 + (((c0 + 1) ^ (r & 7)) << 3);

    const bf16* hfp[2];
    const bf16* hgp[2];
#pragma unroll
    for (int h = 0; h < 2; ++h) {
        int m = m0 + h * 128 + r;
        int bt = m / 65;
        int uu = m - bt * 65;
        int bb = bt >> 8;
        hfp[h] = hf  + (size_t)bt * 640 + kq;
        hgp[h] = hgb + (size_t)(bb * 65 + uu) * 640 + kq;
    }

    // --- wave mapping: 2 (M) x 4 (N) waves, wave tile 128x64 ---
    const int wid = tid >> 6, lane = tid & 63;
    const int wr = wid >> 2, wc = wid & 3;
    const int lg = lane >> 4, l15 = lane & 15;

    bf16x8 F0[2], F1[2], G0[2], G1[2];
    bf16x8 afr[4], bfr[4];
    f32x4 acc[8][4] = {};

    auto loadA = [&](int k0) {
#pragma unroll
        for (int h = 0; h < 2; ++h) {
            F0[h] = *(const bf16x8*)(hfp[h] + k0);
            F1[h] = *(const bf16x8*)(hfp[h] + k0 + 8);
            G0[h] = *(const bf16x8*)(hgp[h] + k0);
            G1[h] = *(const bf16x8*)(hgp[h] + k0 + 8);
        }
    };
    auto stageB2 = [&](int buf, int k0, int call0) {
        const char* w2b = (const char*)W2T + (size_t)k0 * 2;
#pragma unroll
        for (int call = call0; call < call0 + 2; ++call) {
            int chunk = call * 512 + tid;          // 0..2047
            int brow = chunk >> 3, c = chunk & 7;
            const char* src = w2b + (size_t)(n0 + brow) * 1280
                                  + ((c ^ (brow & 7)) << 4);
            __builtin_amdgcn_global_load_lds(
                (const __attribute__((address_space(1))) uint32_t*)src,
                (__attribute__((address_space(3))) uint32_t*)&Bs[buf][chunk << 3],
                16, 0, 0);
        }
    };
    auto genA = [&](int buf) {
#pragma unroll
        for (int h = 0; h < 2; ++h) {
            bf16x8 O0, O1;
#pragma unroll
            for (int i = 0; i < 8; ++i) {
                float s = (float)F0[h][i] + (float)G0[h][i];
                O0[i] = (bf16)fmaxf(s, 0.f);
            }
#pragma unroll
            for (int i = 0; i < 8; ++i) {
                float s = (float)F1[h][i] + (float)G1[h][i];
                O1[i] = (bf16)fmaxf(s, 0.f);
            }
            *(bf16x8*)&As[buf][h * 128 * 64 + aoff0] = O0;
            *(bf16x8*)&As[buf][h * 128 * 64 + aoff1] = O1;
        }
    };

#define LDB(cur, KK)                                                          \
    { const int clog = ((KK) << 2) + lg;                                      \
      _Pragma("unroll")                                                       \
      for (int ni = 0; ni < 4; ++ni) {                                        \
          int row = wc * 64 + ni * 16 + l15;                                  \
          bfr[ni] = *(const bf16x8*)&Bs[cur][row * 64 + ((clog ^ (row & 7)) << 3)]; \
      } }

#define LDA(cur, KK, MH)                                                      \
    { const int clog = ((KK) << 2) + lg;                                      \
      _Pragma("unroll")                                                       \
      for (int i = 0; i < 4; ++i) {                                           \
          int row = wr * 128 + ((MH) * 4 + i) * 16 + l15;                     \
          afr[i] = *(const bf16x8*)&As[cur][row * 64 + ((clog ^ (row & 7)) << 3)]; \
      } }

#define MFMA16(MH)                                                            \
    { __builtin_amdgcn_s_setprio(1);                                          \
      _Pragma("unroll")                                                       \
      for (int i = 0; i < 4; ++i)                                             \
          _Pragma("unroll")                                                   \
          for (int ni = 0; ni < 4; ++ni)                                      \
              acc[(MH) * 4 + i][ni] = __builtin_amdgcn_mfma_f32_16x16x32_bf16(\
                  afr[i], bfr[ni], acc[(MH) * 4 + i][ni], 0, 0, 0);           \
      __builtin_amdgcn_s_setprio(0); }

    // ---- prologue: tile 0 into buffer 0 ----
    loadA(0);
    stageB2(0, 0, 0);
    stageB2(0, 0, 2);
    WAIT_VM(4);        // A-loads done (4 B-DMAs outstanding)
    genA(0);
    WAIT_VM(0);        // B(0) DMA done
    WAIT_LGKM0();      // own ds_writes drained
    BARRIER();

    // ---- main loop: 10 K-tiles, 4 phases each ----
    for (int t = 0; t < 10; ++t) {
        const int cur = t & 1, nxt = cur ^ 1;
        const int kn = (t + 1) * 64;
        // P0: kk=0, mh=0
        if (t < 9) loadA(kn);                 // 8 global loads -> regs
        LDB(cur, 0); LDA(cur, 0, 0);
        BARRIER(); WAIT_LGKM0();
        MFMA16(0);
        BARRIER();
        // P1: kk=0, mh=1
        if (t < 9) stageB2(nxt, kn, 0);       // 2 B-DMAs in flight
        LDA(cur, 0, 1);
        BARRIER(); WAIT_LGKM0();
        MFMA16(1);
        BARRIER();
        // P2: kk=1, mh=0
        if (t < 9) stageB2(nxt, kn, 2);       // +2 B-DMAs
        LDB(cur, 1); LDA(cur, 1, 0);
        BARRIER(); WAIT_LGKM0();
        MFMA16(0);
        BARRIER();
        // P3: kk=1, mh=1
        LDA(cur, 1, 1);
        BARRIER(); WAIT_LGKM0();
        MFMA16(1);
        // tile tail: finish A-gen for t+1, drain B(t+1), one sync
        if (t < 9) {
            WAIT_VM(4);                       // A-loads done, B-DMAs may fly
            genA(nxt);                        // VALU + ds_write (covers B lat)
        }
        WAIT_VM(0);                           // own B-DMAs landed in LDS
        WAIT_LGKM0();                         // own ds_writes visible
        BARRIER();
    }

#undef LDB
#undef LDA
#undef MFMA16

    // ---- epilogue: +b2, fp32 stores ----
    float bv[4];
#pragma unroll
    for (int ni = 0; ni < 4; ++ni) bv[ni] = b2[n0 + wc * 64 + ni * 16 + l15];
#pragma unroll
    for (int mi = 0; mi < 8; ++mi) {
#pragma unroll
        for (int ni = 0; ni < 4; ++ni) {
            int col = n0 + wc * 64 + ni * 16 + l15;
#pragma unroll
            for (int j = 0; j < 4; ++j) {
                int row = m0 + wr * 128 + mi * 16 + lg * 4 + j;
                out[(size_t)row * 1024 + col] = acc[mi][ni][j] + bv[ni];
            }
        }
    }
}

// ---------------------------------------------------------------------------
extern "C" void kernel_launch(void* const* d_in, const int* in_sizes, int n_in,
                              void* d_out, int out_size, void* d_ws, size_t ws_size,
                              hipStream_t stream)
{
    const float* f  = (const float*)d_in[0];   // (8,256,1024)
    const float* g  = (const float*)d_in[1];   // (8,65,320)
    const float* W1 = (const float*)d_in[2];   // (1344,640)
    const float* b1 = (const float*)d_in[3];   // (640)
    const float* W2 = (const float*)d_in[4];   // (640,1024)
    const float* b2 = (const float*)d_in[5];   // (1024)
    float* out = (float*)d_out;                // (8,256,65,1024)

    bf16* hf  = (bf16*)d_ws;                   // 2048*640
    bf16* hgb = hf + 2048 * 640;               // 520*640 (g@W1g + b1)
    bf16* W2T = hgb + 520 * 640;               // 1024*640

    gemm_small<<<dim3(32, 10), 256, 0, stream>>>(f, W1, nullptr, hf, 2048, 640, 1024);
    gemm_small<<<dim3(9, 10), 256, 0, stream>>>(g, W1 + 1024 * 640, b1, hgb, 520, 640, 320);
    w2_transpose<<<dim3(32, 20), dim3(32, 8), 0, stream>>>(W2, W2T);
    joint_main<<<dim3(4, 520), 512, 0, stream>>>(hf, hgb, W2T, b2, out);
}

// Round 4
// 442.573 us; speedup vs baseline: 1.0225x; 1.0225x over previous
//
#include <hip/hip_runtime.h>
#include <cstdint>

typedef __bf16 bf16;
typedef __bf16 bf16x8 __attribute__((ext_vector_type(8)));
typedef float  f32x4  __attribute__((ext_vector_type(4)));

#define BARRIER()    asm volatile("s_barrier" ::: "memory")
#define WAIT_LGKM0() do { asm volatile("s_waitcnt lgkmcnt(0)" ::: "memory"); \
                          __builtin_amdgcn_sched_barrier(0); } while (0)
#define WAIT_VM(n)   do { asm volatile("s_waitcnt vmcnt(" #n ")" ::: "memory"); \
                          __builtin_amdgcn_sched_barrier(0); } while (0)

// ---------------------------------------------------------------------------
// Stage 1a/1b: small fp32 GEMMs -> bf16 output.  C = A(MxK) @ B(KxN) [+bias]
// ---------------------------------------------------------------------------
__global__ __launch_bounds__(256) void gemm_small(
    const float* __restrict__ A, const float* __restrict__ Bm,
    const float* __restrict__ bias, bf16* __restrict__ Cout,
    int M, int N, int K)
{
    __shared__ float As[64][20];
    __shared__ float Bs[16][68];
    const int tid = threadIdx.x;
    const int m0 = blockIdx.x * 64, n0 = blockIdx.y * 64;
    const int tx = tid & 15, ty = tid >> 4;
    const int arow = tid >> 2, ak = (tid & 3) << 2;
    const int bk = tid >> 4, bc = (tid & 15) << 2;
    const bool avalid = (m0 + arow) < M;
    float acc[4][4] = {};

    for (int k0 = 0; k0 < K; k0 += 16) {
        float4 av = make_float4(0.f, 0.f, 0.f, 0.f);
        if (avalid) av = *(const float4*)&A[(size_t)(m0 + arow) * K + k0 + ak];
        float4 bv = *(const float4*)&Bm[(size_t)(k0 + bk) * N + n0 + bc];
        __syncthreads();
        *(float4*)&As[arow][ak] = av;
        *(float4*)&Bs[bk][bc] = bv;
        __syncthreads();
#pragma unroll
        for (int k = 0; k < 16; ++k) {
            float a[4], b[4];
#pragma unroll
            for (int i = 0; i < 4; ++i) a[i] = As[ty * 4 + i][k];
#pragma unroll
            for (int j = 0; j < 4; ++j) b[j] = Bs[k][tx * 4 + j];
#pragma unroll
            for (int i = 0; i < 4; ++i)
#pragma unroll
                for (int j = 0; j < 4; ++j) acc[i][j] += a[i] * b[j];
        }
    }
#pragma unroll
    for (int i = 0; i < 4; ++i) {
        int row = m0 + ty * 4 + i;
        if (row >= M) continue;
#pragma unroll
        for (int j = 0; j < 4; ++j) {
            int col = n0 + tx * 4 + j;
            float v = acc[i][j] + (bias ? bias[col] : 0.f);
            Cout[(size_t)row * N + col] = (bf16)v;
        }
    }
}

// ---------------------------------------------------------------------------
// Stage 1c: W2 (640x1024 fp32) -> W2T (1024x640 bf16)
// ---------------------------------------------------------------------------
__global__ __launch_bounds__(256) void w2_transpose(
    const float* __restrict__ W2, bf16* __restrict__ W2T)
{
    __shared__ float t[32][33];
    const int tx = threadIdx.x, ty = threadIdx.y;
    const int n0 = blockIdx.x * 32, k0 = blockIdx.y * 32;
#pragma unroll
    for (int i = 0; i < 4; ++i)
        t[ty + i * 8][tx] = W2[(size_t)(k0 + ty + i * 8) * 1024 + n0 + tx];
    __syncthreads();
#pragma unroll
    for (int i = 0; i < 4; ++i)
        W2T[(size_t)(n0 + ty + i * 8) * 640 + k0 + tx] = (bf16)t[tx][ty + i * 8];
}

// ---------------------------------------------------------------------------
// Stage 2: fused joint GEMM. m201-style 4-phase/K-tile schedule with COUNTED
// vmem discipline: all vmem for tile t+1 issued at P0; the ONLY vm-wait is in
// P2 (loads are ~2 phases old -> lands free). genA halves live inside P2/P3
// after that phase's ds_reads; ds_writes drained by the pre-MFMA lgkm0.
// No drain-at-tail, no __syncthreads in the loop.
// BM=256 BN=256 BK=64, 512 thr = 8 waves (2Mx4N), wave tile 128x64,
// LDS 128 KB double-buffered, XOR-swizzle (16B slot ^= row&7), 0 conflicts.
// ---------------------------------------------------------------------------
__global__ __launch_bounds__(512, 2) void joint_main(
    const bf16* __restrict__ hf, const bf16* __restrict__ hgb,
    const bf16* __restrict__ W2T, const float* __restrict__ b2,
    float* __restrict__ out)
{
    __shared__ bf16 As[2][256 * 64];   // 2 x 32 KB
    __shared__ bf16 Bs[2][256 * 64];   // 2 x 32 KB
    const int tid = threadIdx.x;
    const int n0 = blockIdx.x * 256;
    const int m0 = blockIdx.y * 256;

    // --- A-generation mapping: thread -> (row r in half, k-quarter) ---
    const int r  = tid >> 2;               // 0..127
    const int kq = (tid & 3) << 4;         // 0,16,32,48
    const int c0 = (tid & 3) << 1;         // 16B-chunk indices c0, c0+1
    const int aoff0 = r * 64 + (((c0    ) ^ (r & 7)) << 3);
    const int aoff1 = r * 64 + (((c0 + 1) ^ (r & 7)) << 3);

    const bf16* hfp[2];
    const bf16* hgp[2];
#pragma unroll
    for (int h = 0; h < 2; ++h) {
        int m = m0 + h * 128 + r;
        int bt = m / 65;
        int uu = m - bt * 65;
        int bb = bt >> 8;
        hfp[h] = hf  + (size_t)bt * 640 + kq;
        hgp[h] = hgb + (size_t)(bb * 65 + uu) * 640 + kq;
    }

    // --- wave mapping: 2 (M) x 4 (N) waves, wave tile 128x64 ---
    const int wid = tid >> 6, lane = tid & 63;
    const int wr = wid >> 2, wc = wid & 3;
    const int lg = lane >> 4, l15 = lane & 15;

    bf16x8 F0[2], F1[2], G0[2], G1[2];
    bf16x8 afr[4], bfr[4];
    f32x4 acc[8][4] = {};

    auto loadA = [&](int k0) {
#pragma unroll
        for (int h = 0; h < 2; ++h) {
            F0[h] = *(const bf16x8*)(hfp[h] + k0);
            F1[h] = *(const bf16x8*)(hfp[h] + k0 + 8);
            G0[h] = *(const bf16x8*)(hgp[h] + k0);
            G1[h] = *(const bf16x8*)(hgp[h] + k0 + 8);
        }
    };
    auto stageB4 = [&](int buf, int k0) {
        const char* w2b = (const char*)W2T + (size_t)k0 * 2;
#pragma unroll
        for (int call = 0; call < 4; ++call) {
            int chunk = call * 512 + tid;          // 0..2047
            int brow = chunk >> 3, c = chunk & 7;
            const char* src = w2b + (size_t)(n0 + brow) * 1280
                                  + ((c ^ (brow & 7)) << 4);
            __builtin_amdgcn_global_load_lds(
                (const __attribute__((address_space(1))) uint32_t*)src,
                (__attribute__((address_space(3))) uint32_t*)&Bs[buf][chunk << 3],
                16, 0, 0);
        }
    };
    auto genA_h = [&](int buf, int h) {
        bf16x8 O0, O1;
#pragma unroll
        for (int i = 0; i < 8; ++i) {
            float s = (float)F0[h][i] + (float)G0[h][i];
            O0[i] = (bf16)fmaxf(s, 0.f);
        }
#pragma unroll
        for (int i = 0; i < 8; ++i) {
            float s = (float)F1[h][i] + (float)G1[h][i];
            O1[i] = (bf16)fmaxf(s, 0.f);
        }
        *(bf16x8*)&As[buf][h * 128 * 64 + aoff0] = O0;
        *(bf16x8*)&As[buf][h * 128 * 64 + aoff1] = O1;
    };

#define LDB(cur, KK)                                                          \
    { const int clog = ((KK) << 2) + lg;                                      \
      _Pragma("unroll")                                                       \
      for (int ni = 0; ni < 4; ++ni) {                                        \
          int row = wc * 64 + ni * 16 + l15;                                  \
          bfr[ni] = *(const bf16x8*)&Bs[cur][row * 64 + ((clog ^ (row & 7)) << 3)]; \
      } }

#define LDA(cur, KK, MH)                                                      \
    { const int clog = ((KK) << 2) + lg;                                      \
      _Pragma("unroll")                                                       \
      for (int i = 0; i < 4; ++i) {                                           \
          int row = wr * 128 + ((MH) * 4 + i) * 16 + l15;                     \
          afr[i] = *(const bf16x8*)&As[cur][row * 64 + ((clog ^ (row & 7)) << 3)]; \
      } }

#define MFMA16(MH)                                                            \
    { __builtin_amdgcn_s_setprio(1);                                          \
      _Pragma("unroll")                                                       \
      for (int i = 0; i < 4; ++i)                                             \
          _Pragma("unroll")                                                   \
          for (int ni = 0; ni < 4; ++ni)                                      \
              acc[(MH) * 4 + i][ni] = __builtin_amdgcn_mfma_f32_16x16x32_bf16(\
                  afr[i], bfr[ni], acc[(MH) * 4 + i][ni], 0, 0, 0);           \
      __builtin_amdgcn_s_setprio(0); }

    // ---- prologue: tile 0 into buffer 0 ----
    stageB4(0, 0);
    loadA(0);
    WAIT_VM(0);
    genA_h(0, 0);
    genA_h(0, 1);
    WAIT_LGKM0();
    BARRIER();

    // ---- main loop: 10 K-tiles, 4 phases each, counted-vm discipline ----
    for (int t = 0; t < 10; ++t) {
        const int cur = t & 1, nxt = cur ^ 1;
        const int kn = (t + 1) * 64;
        // P0: issue ALL of tile t+1's vmem (4 B-DMAs + 8 A-loads)
        if (t < 9) { stageB4(nxt, kn); loadA(kn); }
        LDB(cur, 0); LDA(cur, 0, 0);
        BARRIER(); WAIT_LGKM0();
        MFMA16(0);
        BARRIER();
        // P1
        LDA(cur, 0, 1);
        BARRIER(); WAIT_LGKM0();
        MFMA16(1);
        BARRIER();
        // P2: the only vm-wait (loads ~2 phases old); genA half 0 overlaps reads
        LDB(cur, 1); LDA(cur, 1, 0);
        if (t < 9) { WAIT_VM(0); genA_h(nxt, 0); }
        BARRIER(); WAIT_LGKM0();
        MFMA16(0);
        BARRIER();
        // P3: genA half 1; its ds_writes drained by the pre-MFMA lgkm0
        LDA(cur, 1, 1);
        if (t < 9) genA_h(nxt, 1);
        BARRIER(); WAIT_LGKM0();
        MFMA16(1);
        BARRIER();
    }

#undef LDB
#undef LDA
#undef MFMA16

    // ---- epilogue: +b2, fp32 stores ----
    float bv[4];
#pragma unroll
    for (int ni = 0; ni < 4; ++ni) bv[ni] = b2[n0 + wc * 64 + ni * 16 + l15];
#pragma unroll
    for (int mi = 0; mi < 8; ++mi) {
#pragma unroll
        for (int ni = 0; ni < 4; ++ni) {
            int col = n0 + wc * 64 + ni * 16 + l15;
#pragma unroll
            for (int j = 0; j < 4; ++j) {
                int row = m0 + wr * 128 + mi * 16 + lg * 4 + j;
                out[(size_t)row * 1024 + col] = acc[mi][ni][j] + bv[ni];
            }
        }
    }
}

// ---------------------------------------------------------------------------
extern "C" void kernel_launch(void* const* d_in, const int* in_sizes, int n_in,
                              void* d_out, int out_size, void* d_ws, size_t ws_size,
                              hipStream_t stream)
{
    const float* f  = (const float*)d_in[0];   // (8,256,1024)
    const float* g  = (const float*)d_in[1];   // (8,65,320)
    const float* W1 = (const float*)d_in[2];   // (1344,640)
    const float* b1 = (const float*)d_in[3];   // (640)
    const float* W2 = (const float*)d_in[4];   // (640,1024)
    const float* b2 = (const float*)d_in[5];   // (1024)
    float* out = (float*)d_out;                // (8,256,65,1024)

    bf16* hf  = (bf16*)d_ws;                   // 2048*640
    bf16* hgb = hf + 2048 * 640;               // 520*640 (g@W1g + b1)
    bf16* W2T = hgb + 520 * 640;               // 1024*640

    gemm_small<<<dim3(32, 10), 256, 0, stream>>>(f, W1, nullptr, hf, 2048, 640, 1024);
    gemm_small<<<dim3(9, 10), 256, 0, stream>>>(g, W1 + 1024 * 640, b1, hgb, 520, 640, 320);
    w2_transpose<<<dim3(32, 20), dim3(32, 8), 0, stream>>>(W2, W2T);
    joint_main<<<dim3(4, 520), 512, 0, stream>>>(hf, hgb, W2T, b2, out);
}

// Round 5
// 426.601 us; speedup vs baseline: 1.0607x; 1.0374x over previous
//
#include <hip/hip_runtime.h>
#include <cstdint>

typedef __bf16 bf16;
typedef __bf16 bf16x8 __attribute__((ext_vector_type(8)));
typedef float  f32x4  __attribute__((ext_vector_type(4)));

#define BARRIER()    asm volatile("s_barrier" ::: "memory")
#define WAIT_LGKM0() asm volatile("s_waitcnt lgkmcnt(0)" ::: "memory")
#define WAIT_VM(n)   asm volatile("s_waitcnt vmcnt(" #n ")" ::: "memory")

// ---------------------------------------------------------------------------
// Fused prep kernel: hf-GEMM (320 blocks) | hg-GEMM (90) | W2 transpose (640).
// One dispatch instead of three (cuts launch gaps).
// ---------------------------------------------------------------------------
__device__ void gemm_small_body(
    const float* __restrict__ A, const float* __restrict__ Bm,
    const float* __restrict__ bias, bf16* __restrict__ Cout,
    int M, int N, int K, int bx, int by)
{
    __shared__ float As[64][20];
    __shared__ float Bs[16][68];
    const int tid = threadIdx.x;
    const int m0 = bx * 64, n0 = by * 64;
    const int tx = tid & 15, ty = tid >> 4;
    const int arow = tid >> 2, ak = (tid & 3) << 2;
    const int bk = tid >> 4, bc = (tid & 15) << 2;
    const bool avalid = (m0 + arow) < M;
    float acc[4][4] = {};

    for (int k0 = 0; k0 < K; k0 += 16) {
        float4 av = make_float4(0.f, 0.f, 0.f, 0.f);
        if (avalid) av = *(const float4*)&A[(size_t)(m0 + arow) * K + k0 + ak];
        float4 bv = *(const float4*)&Bm[(size_t)(k0 + bk) * N + n0 + bc];
        __syncthreads();
        *(float4*)&As[arow][ak] = av;
        *(float4*)&Bs[bk][bc] = bv;
        __syncthreads();
#pragma unroll
        for (int k = 0; k < 16; ++k) {
            float a[4], b[4];
#pragma unroll
            for (int i = 0; i < 4; ++i) a[i] = As[ty * 4 + i][k];
#pragma unroll
            for (int j = 0; j < 4; ++j) b[j] = Bs[k][tx * 4 + j];
#pragma unroll
            for (int i = 0; i < 4; ++i)
#pragma unroll
                for (int j = 0; j < 4; ++j) acc[i][j] += a[i] * b[j];
        }
    }
#pragma unroll
    for (int i = 0; i < 4; ++i) {
        int row = m0 + ty * 4 + i;
        if (row >= M) continue;
#pragma unroll
        for (int j = 0; j < 4; ++j) {
            int col = n0 + tx * 4 + j;
            float v = acc[i][j] + (bias ? bias[col] : 0.f);
            Cout[(size_t)row * N + col] = (bf16)v;
        }
    }
}

__device__ void w2t_body(const float* __restrict__ W2, bf16* __restrict__ W2T,
                         int bx, int by)
{
    __shared__ float t[32][33];
    const int tx = threadIdx.x & 31, ty = threadIdx.x >> 5;  // 32 x 8
    const int n0 = bx * 32, k0 = by * 32;
#pragma unroll
    for (int i = 0; i < 4; ++i)
        t[ty + i * 8][tx] = W2[(size_t)(k0 + ty + i * 8) * 1024 + n0 + tx];
    __syncthreads();
#pragma unroll
    for (int i = 0; i < 4; ++i)
        W2T[(size_t)(n0 + ty + i * 8) * 640 + k0 + tx] = (bf16)t[tx][ty + i * 8];
}

__global__ __launch_bounds__(256) void prep(
    const float* __restrict__ f, const float* __restrict__ g,
    const float* __restrict__ W1, const float* __restrict__ b1,
    const float* __restrict__ W2,
    bf16* __restrict__ hf, bf16* __restrict__ hgb, bf16* __restrict__ W2T)
{
    const int bid = blockIdx.x;
    if (bid < 320) {                       // hf = f @ W1[:1024]   (32 x 10)
        gemm_small_body(f, W1, nullptr, hf, 2048, 640, 1024, bid % 32, bid / 32);
    } else if (bid < 410) {                // hgb = g @ W1[1024:] + b1  (9 x 10)
        int b = bid - 320;
        gemm_small_body(g, W1 + 1024 * 640, b1, hgb, 520, 640, 320, b % 9, b / 9);
    } else {                               // W2T  (32 x 20)
        int b = bid - 410;
        w2t_body(W2, W2T, b % 32, b / 32);
    }
}

// ---------------------------------------------------------------------------
// Stage 2: fused joint GEMM. R1 geometry (3 blocks/CU) + deep prefetch.
// BM=128 BN=256 BK=64, 512 thr = 8 waves (2Mx4N), wave tile 64x64.
// LDS 48 KB single-buffer: As[128x64] + Bs[256x64], XOR-swizzled 16B chunks.
// Schedule per tile t (2 barriers, counted vmcnt, ping-pong A-source regs):
//   loadA(t+1) -> other reg set          (issued BEFORE genA: full-tile flight)
//   genA(t): regs -> VALU -> ds_write As (auto-waits loads(t), a tile old)
//   WAIT_VM(8)  = DMA(t) landed          (loads(t+1) stay in flight)
//   WAIT_LGKM0; BARRIER
//   MFMA phase: ds_read + 32 MFMA/wave   (compiler-scheduled lgkm waits)
//   BARRIER
//   stageB_DMA(t+1)                      (Bs free; waited next tile)
// ---------------------------------------------------------------------------
__global__ __launch_bounds__(512) void joint_main(
    const bf16* __restrict__ hf, const bf16* __restrict__ hgb,
    const bf16* __restrict__ W2T, const float* __restrict__ b2,
    float* __restrict__ out)
{
    __shared__ bf16 As[128 * 64];   // 16 KB
    __shared__ bf16 Bs[256 * 64];   // 32 KB
    const int tid = threadIdx.x;
    const int n0 = blockIdx.x * 256;
    const int m0 = blockIdx.y * 128;

    // --- A-generation mapping: thread -> (row r, k-quarter) ---
    const int r  = tid >> 2;               // 0..127
    const int kq = (tid & 3) << 4;         // 0,16,32,48
    const int c0 = (tid & 3) << 1;         // 16B-chunk indices c0, c0+1
    const int aoff0 = r * 64 + (((c0    ) ^ (r & 7)) << 3);
    const int aoff1 = r * 64 + (((c0 + 1) ^ (r & 7)) << 3);

    const int m  = m0 + r;
    const int bt = m / 65;
    const int uu = m - bt * 65;
    const int bb = bt >> 8;
    const bf16* hfp = hf  + (size_t)bt * 640 + kq;
    const bf16* hgp = hgb + (size_t)(bb * 65 + uu) * 640 + kq;

    // --- wave mapping: 2 (M) x 4 (N), wave tile 64x64 ---
    const int wid = tid >> 6, lane = tid & 63;
    const int wr = wid >> 2, wc = wid & 3;
    const int lg = lane >> 4, l15 = lane & 15;

    f32x4 acc[4][4] = {};

    auto loadA = [&](int k0, bf16x8& F0, bf16x8& F1, bf16x8& G0, bf16x8& G1) {
        F0 = *(const bf16x8*)(hfp + k0);
        F1 = *(const bf16x8*)(hfp + k0 + 8);
        G0 = *(const bf16x8*)(hgp + k0);
        G1 = *(const bf16x8*)(hgp + k0 + 8);
    };
    auto stageB = [&](int k0) {
        const char* w2b = (const char*)W2T + (size_t)k0 * 2;
#pragma unroll
        for (int call = 0; call < 4; ++call) {
            int chunk = call * 512 + tid;          // 0..2047
            int brow = chunk >> 3, c = chunk & 7;
            const char* src = w2b + (size_t)(n0 + brow) * 1280
                                  + ((c ^ (brow & 7)) << 4);
            __builtin_amdgcn_global_load_lds(
                (const __attribute__((address_space(1))) uint32_t*)src,
                (__attribute__((address_space(3))) uint32_t*)&Bs[chunk << 3],
                16, 0, 0);
        }
    };
    auto genA = [&](const bf16x8& F0, const bf16x8& F1,
                    const bf16x8& G0, const bf16x8& G1) {
        bf16x8 O0, O1;
#pragma unroll
        for (int i = 0; i < 8; ++i) {
            float s = (float)F0[i] + (float)G0[i];
            O0[i] = (bf16)fmaxf(s, 0.f);
        }
#pragma unroll
        for (int i = 0; i < 8; ++i) {
            float s = (float)F1[i] + (float)G1[i];
            O1[i] = (bf16)fmaxf(s, 0.f);
        }
        *(bf16x8*)&As[aoff0] = O0;
        *(bf16x8*)&As[aoff1] = O1;
    };
    auto mfmaPhase = [&]() {
#pragma unroll
        for (int kk = 0; kk < 2; ++kk) {
            const int clog = (kk << 2) + lg;
            bf16x8 bfr[4], afr[4];
#pragma unroll
            for (int ni = 0; ni < 4; ++ni) {
                int row = wc * 64 + ni * 16 + l15;
                bfr[ni] = *(const bf16x8*)&Bs[row * 64 + ((clog ^ (row & 7)) << 3)];
            }
#pragma unroll
            for (int mi = 0; mi < 4; ++mi) {
                int row = wr * 64 + mi * 16 + l15;
                afr[mi] = *(const bf16x8*)&As[row * 64 + ((clog ^ (row & 7)) << 3)];
            }
#pragma unroll
            for (int mi = 0; mi < 4; ++mi)
#pragma unroll
                for (int ni = 0; ni < 4; ++ni)
                    acc[mi][ni] = __builtin_amdgcn_mfma_f32_16x16x32_bf16(
                        afr[mi], bfr[ni], acc[mi][ni], 0, 0, 0);
        }
    };

    bf16x8 Fa0, Fa1, Ga0, Ga1;   // ping
    bf16x8 Fb0, Fb1, Gb0, Gb1;   // pong

    // ---- prologue: queue = [loads(0) x8, DMA(0) x4] ----
    loadA(0, Fa0, Fa1, Ga0, Ga1);
    stageB(0);

    // ---- main loop: 10 tiles, unrolled x2 for static reg ping-pong ----
#pragma unroll 1
    for (int tt = 0; tt < 5; ++tt) {
        const int t0 = tt * 2;
        // ---- even tile (uses A-set, loads into B-set) ----
        if (t0 + 1 < 10) loadA((t0 + 1) * 64, Fb0, Fb1, Gb0, Gb1);
        genA(Fa0, Fa1, Ga0, Ga1);        // auto-waits loads(t0) (oldest)
        WAIT_VM(8);                       // DMA(t0) landed; loads(t0+1) fly
        WAIT_LGKM0();
        BARRIER();
        mfmaPhase();
        BARRIER();
        if (t0 + 1 < 10) stageB((t0 + 1) * 64);
        // ---- odd tile ----
        if (t0 + 2 < 10) loadA((t0 + 2) * 64, Fa0, Fa1, Ga0, Ga1);
        genA(Fb0, Fb1, Gb0, Gb1);
        if (t0 + 2 < 10) { WAIT_VM(8); } else { WAIT_VM(0); }
        WAIT_LGKM0();
        BARRIER();
        mfmaPhase();
        BARRIER();
        if (t0 + 2 < 10) stageB((t0 + 2) * 64);
    }

    // ---- epilogue: +b2, fp32 stores ----
    float bv[4];
#pragma unroll
    for (int ni = 0; ni < 4; ++ni) bv[ni] = b2[n0 + wc * 64 + ni * 16 + l15];
#pragma unroll
    for (int mi = 0; mi < 4; ++mi) {
#pragma unroll
        for (int ni = 0; ni < 4; ++ni) {
            int col = n0 + wc * 64 + ni * 16 + l15;
#pragma unroll
            for (int j = 0; j < 4; ++j) {
                int row = m0 + wr * 64 + mi * 16 + lg * 4 + j;
                out[(size_t)row * 1024 + col] = acc[mi][ni][j] + bv[ni];
            }
        }
    }
}

// ---------------------------------------------------------------------------
extern "C" void kernel_launch(void* const* d_in, const int* in_sizes, int n_in,
                              void* d_out, int out_size, void* d_ws, size_t ws_size,
                              hipStream_t stream)
{
    const float* f  = (const float*)d_in[0];   // (8,256,1024)
    const float* g  = (const float*)d_in[1];   // (8,65,320)
    const float* W1 = (const float*)d_in[2];   // (1344,640)
    const float* b1 = (const float*)d_in[3];   // (640)
    const float* W2 = (const float*)d_in[4];   // (640,1024)
    const float* b2 = (const float*)d_in[5];   // (1024)
    float* out = (float*)d_out;                // (8,256,65,1024)

    bf16* hf  = (bf16*)d_ws;                   // 2048*640
    bf16* hgb = hf + 2048 * 640;               // 520*640 (g@W1g + b1)
    bf16* W2T = hgb + 520 * 640;               // 1024*640

    prep<<<1050, 256, 0, stream>>>(f, g, W1, b1, W2, hf, hgb, W2T);
    joint_main<<<dim3(4, 1040), 512, 0, stream>>>(hf, hgb, W2T, b2, out);
}

// Round 6
// 325.641 us; speedup vs baseline: 1.3896x; 1.3100x over previous
//
#include <hip/hip_runtime.h>
#include <cstdint>

typedef __bf16 bf16;
typedef __bf16 bf16x8 __attribute__((ext_vector_type(8)));
typedef float  f32x4  __attribute__((ext_vector_type(4)));

#define BARRIER()    asm volatile("s_barrier" ::: "memory")
#define WAIT_LGKM0() asm volatile("s_waitcnt lgkmcnt(0)" ::: "memory")
#define WAIT_VM(n)   asm volatile("s_waitcnt vmcnt(" #n ")" ::: "memory")

// ---------------------------------------------------------------------------
// Fused prep kernel: hf-GEMM (320 blocks) | hg-GEMM (90) | W2 transpose (640).
// ---------------------------------------------------------------------------
__device__ void gemm_small_body(
    const float* __restrict__ A, const float* __restrict__ Bm,
    const float* __restrict__ bias, bf16* __restrict__ Cout,
    int M, int N, int K, int bx, int by)
{
    __shared__ float As[64][20];
    __shared__ float Bs[16][68];
    const int tid = threadIdx.x;
    const int m0 = bx * 64, n0 = by * 64;
    const int tx = tid & 15, ty = tid >> 4;
    const int arow = tid >> 2, ak = (tid & 3) << 2;
    const int bk = tid >> 4, bc = (tid & 15) << 2;
    const bool avalid = (m0 + arow) < M;
    float acc[4][4] = {};

    for (int k0 = 0; k0 < K; k0 += 16) {
        float4 av = make_float4(0.f, 0.f, 0.f, 0.f);
        if (avalid) av = *(const float4*)&A[(size_t)(m0 + arow) * K + k0 + ak];
        float4 bv = *(const float4*)&Bm[(size_t)(k0 + bk) * N + n0 + bc];
        __syncthreads();
        *(float4*)&As[arow][ak] = av;
        *(float4*)&Bs[bk][bc] = bv;
        __syncthreads();
#pragma unroll
        for (int k = 0; k < 16; ++k) {
            float a[4], b[4];
#pragma unroll
            for (int i = 0; i < 4; ++i) a[i] = As[ty * 4 + i][k];
#pragma unroll
            for (int j = 0; j < 4; ++j) b[j] = Bs[k][tx * 4 + j];
#pragma unroll
            for (int i = 0; i < 4; ++i)
#pragma unroll
                for (int j = 0; j < 4; ++j) acc[i][j] += a[i] * b[j];
        }
    }
#pragma unroll
    for (int i = 0; i < 4; ++i) {
        int row = m0 + ty * 4 + i;
        if (row >= M) continue;
#pragma unroll
        for (int j = 0; j < 4; ++j) {
            int col = n0 + tx * 4 + j;
            float v = acc[i][j] + (bias ? bias[col] : 0.f);
            Cout[(size_t)row * N + col] = (bf16)v;
        }
    }
}

__device__ void w2t_body(const float* __restrict__ W2, bf16* __restrict__ W2T,
                         int bx, int by)
{
    __shared__ float t[32][33];
    const int tx = threadIdx.x & 31, ty = threadIdx.x >> 5;  // 32 x 8
    const int n0 = bx * 32, k0 = by * 32;
#pragma unroll
    for (int i = 0; i < 4; ++i)
        t[ty + i * 8][tx] = W2[(size_t)(k0 + ty + i * 8) * 1024 + n0 + tx];
    __syncthreads();
#pragma unroll
    for (int i = 0; i < 4; ++i)
        W2T[(size_t)(n0 + ty + i * 8) * 640 + k0 + tx] = (bf16)t[tx][ty + i * 8];
}

__global__ __launch_bounds__(256) void prep(
    const float* __restrict__ f, const float* __restrict__ g,
    const float* __restrict__ W1, const float* __restrict__ b1,
    const float* __restrict__ W2,
    bf16* __restrict__ hf, bf16* __restrict__ hgb, bf16* __restrict__ W2T)
{
    const int bid = blockIdx.x;
    if (bid < 320) {
        gemm_small_body(f, W1, nullptr, hf, 2048, 640, 1024, bid % 32, bid / 32);
    } else if (bid < 410) {
        int b = bid - 320;
        gemm_small_body(g, W1 + 1024 * 640, b1, hgb, 520, 640, 320, b % 9, b / 9);
    } else {
        int b = bid - 410;
        w2t_body(W2, W2T, b % 32, b / 32);
    }
}

// ---------------------------------------------------------------------------
// Stage 2: fused joint GEMM, sized for 3 blocks/CU residency.
// BM=128 BN=128 BK=64, 256 thr = 4 waves (2Mx2N), wave tile 64x64 (64 AGPR).
// LDS 32 KB single-buffer: As[128x64] + Bs[128x64], XOR-swizzle 16B chunks.
// Per tile t:
//   genA(t)  : consume A-source regs -> VALU relu -> swizzled ds_write
//   loadA(t+1): refill the SAME reg set (flight = whole MFMA phase)
//   WAIT_VM(8): B-DMA(t) landed (8 A-loads stay in flight); lgkm0; BARRIER
//   mfmaPhase : ds_read + 32 MFMA/wave (compiler-scheduled waits)
//   BARRIER; stageB(t+1) DMA into Bs (waited next tile)
// Cross-block overlap (3/CU) hides epilogue HBM writes + prologue + skew.
// ---------------------------------------------------------------------------
__global__ __launch_bounds__(256, 3) void joint_main(
    const bf16* __restrict__ hf, const bf16* __restrict__ hgb,
    const bf16* __restrict__ W2T, const float* __restrict__ b2,
    float* __restrict__ out)
{
    __shared__ bf16 As[128 * 64];   // 16 KB
    __shared__ bf16 Bs[128 * 64];   // 16 KB
    const int tid = threadIdx.x;
    const int n0 = blockIdx.x * 128;
    const int m0 = blockIdx.y * 128;

    // --- A-generation mapping: thread -> (row r, k-half of 32 elems) ---
    const int r  = tid >> 1;               // 0..127
    const int kh = (tid & 1) << 5;         // 0 or 32 (bf16 elems)
    const int c0 = (tid & 1) << 2;         // first of 4 16B-chunks (0 or 4)
    int aoff[4];
#pragma unroll
    for (int c = 0; c < 4; ++c)
        aoff[c] = r * 64 + (((c0 + c) ^ (r & 7)) << 3);

    const int m  = m0 + r;
    const int bt = m / 65;
    const int uu = m - bt * 65;
    const int bb = bt >> 8;
    const bf16* hfp = hf  + (size_t)bt * 640 + kh;
    const bf16* hgp = hgb + (size_t)(bb * 65 + uu) * 640 + kh;

    // --- wave mapping: 2 (M) x 2 (N), wave tile 64x64 ---
    const int wid = tid >> 6, lane = tid & 63;
    const int wr = wid >> 1, wc = wid & 1;
    const int lg = lane >> 4, l15 = lane & 15;

    f32x4 acc[4][4] = {};
    bf16x8 F[4], G[4];                      // A-source regs (single set)

    auto loadA = [&](int k0) {
#pragma unroll
        for (int i = 0; i < 2; ++i) {
            F[i] = *(const bf16x8*)(hfp + k0 + i * 8);
            G[i] = *(const bf16x8*)(hgp + k0 + i * 8);
        }
#pragma unroll
        for (int i = 2; i < 4; ++i) {
            F[i] = *(const bf16x8*)(hfp + k0 + i * 8);
            G[i] = *(const bf16x8*)(hgp + k0 + i * 8);
        }
    };
    auto stageB = [&](int k0) {
        const char* w2b = (const char*)W2T + (size_t)k0 * 2;
#pragma unroll
        for (int call = 0; call < 4; ++call) {
            int chunk = call * 256 + tid;          // 0..1023
            int brow = chunk >> 3, c = chunk & 7;
            const char* src = w2b + (size_t)(n0 + brow) * 1280
                                  + ((c ^ (brow & 7)) << 4);
            __builtin_amdgcn_global_load_lds(
                (const __attribute__((address_space(1))) uint32_t*)src,
                (__attribute__((address_space(3))) uint32_t*)&Bs[chunk << 3],
                16, 0, 0);
        }
    };
    auto genA = [&]() {
#pragma unroll
        for (int c = 0; c < 4; ++c) {
            bf16x8 O;
#pragma unroll
            for (int i = 0; i < 8; ++i) {
                float s = (float)F[c][i] + (float)G[c][i];
                O[i] = (bf16)fmaxf(s, 0.f);
            }
            *(bf16x8*)&As[aoff[c]] = O;
        }
    };
    auto mfmaPhase = [&]() {
#pragma unroll
        for (int kk = 0; kk < 2; ++kk) {
            const int clog = (kk << 2) + lg;
            bf16x8 bfr[4], afr[4];
#pragma unroll
            for (int ni = 0; ni < 4; ++ni) {
                int row = wc * 64 + ni * 16 + l15;
                bfr[ni] = *(const bf16x8*)&Bs[row * 64 + ((clog ^ (row & 7)) << 3)];
            }
#pragma unroll
            for (int mi = 0; mi < 4; ++mi) {
                int row = wr * 64 + mi * 16 + l15;
                afr[mi] = *(const bf16x8*)&As[row * 64 + ((clog ^ (row & 7)) << 3)];
            }
#pragma unroll
            for (int mi = 0; mi < 4; ++mi)
#pragma unroll
                for (int ni = 0; ni < 4; ++ni)
                    acc[mi][ni] = __builtin_amdgcn_mfma_f32_16x16x32_bf16(
                        afr[mi], bfr[ni], acc[mi][ni], 0, 0, 0);
        }
    };

    // ---- prologue: loads(0) x8 then DMA(0) x4 ----
    loadA(0);
    stageB(0);

#pragma unroll 1
    for (int t = 0; t < 10; ++t) {
        genA();                            // consume loads(t) (compiler vmcnt)
        if (t < 9) loadA((t + 1) * 64);    // refill; flight = MFMA phase
        if (t < 9) { WAIT_VM(8); } else { WAIT_VM(0); }   // B-DMA(t) landed
        WAIT_LGKM0();                      // ds_writes visible
        BARRIER();
        mfmaPhase();
        BARRIER();
        if (t < 9) stageB((t + 1) * 64);   // DMA(t+1); waited next tile
    }

    // ---- epilogue: +b2, fp32 stores ----
    float bv[4];
#pragma unroll
    for (int ni = 0; ni < 4; ++ni) bv[ni] = b2[n0 + wc * 64 + ni * 16 + l15];
#pragma unroll
    for (int mi = 0; mi < 4; ++mi) {
#pragma unroll
        for (int ni = 0; ni < 4; ++ni) {
            int col = n0 + wc * 64 + ni * 16 + l15;
#pragma unroll
            for (int j = 0; j < 4; ++j) {
                int row = m0 + wr * 64 + mi * 16 + lg * 4 + j;
                out[(size_t)row * 1024 + col] = acc[mi][ni][j] + bv[ni];
            }
        }
    }
}

// ---------------------------------------------------------------------------
extern "C" void kernel_launch(void* const* d_in, const int* in_sizes, int n_in,
                              void* d_out, int out_size, void* d_ws, size_t ws_size,
                              hipStream_t stream)
{
    const float* f  = (const float*)d_in[0];   // (8,256,1024)
    const float* g  = (const float*)d_in[1];   // (8,65,320)
    const float* W1 = (const float*)d_in[2];   // (1344,640)
    const float* b1 = (const float*)d_in[3];   // (640)
    const float* W2 = (const float*)d_in[4];   // (640,1024)
    const float* b2 = (const float*)d_in[5];   // (1024)
    float* out = (float*)d_out;                // (8,256,65,1024)

    bf16* hf  = (bf16*)d_ws;                   // 2048*640
    bf16* hgb = hf + 2048 * 640;               // 520*640 (g@W1g + b1)
    bf16* W2T = hgb + 520 * 640;               // 1024*640

    prep<<<1050, 256, 0, stream>>>(f, g, W1, b1, W2, hf, hgb, W2T);
    joint_main<<<dim3(8, 1040), 256, 0, stream>>>(hf, hgb, W2T, b2, out);
}